// Round 1
// baseline (250.858 us; speedup 1.0000x reference)
//
#include <hip/hip_runtime.h>

#define B_TOTAL 131072
#define N 19
#define BB 13                  // batches per block (13*19 = 247 active threads of 256)
#define ROWS (BB * N)          // 247
#define NPAD 20                // padded row: 80 B, 16B-aligned rows for float4 LDS reads
#define OUT_PER_G (BB * N * N) // 4693 floats staged per block
#define NBLOCKS ((B_TOTAL + BB - 1) / BB)  // 10083 (last block: 6 valid batches)

typedef __attribute__((ext_vector_type(16))) float sfloat16;
typedef __attribute__((ext_vector_type(2)))  float sfloat2;

// One block = 13 batches. One thread = one (batch, query-row i).
//   out[b,i,k] = feat[b,k] + bo[k] + invZ_i * sum_j exp(a_i*K_j - m_i)*V_j*Wo[k,j]
// v2 theory: v1 was VMEM-issue-bound (~440 per-wave vector loads/thread for
// weights ~= 115 us). Fix: Wo rows via inline-asm s_load into SGPRs (scalar
// pipe, FMA's one scalar operand), Wq/Wk/Wv staged in LDS (per-lane rows,
// b128 reads ~2-way banked = free), bo via LDS broadcast, feat re-read from
// LDS in the epilogue (drops f[20] liveness across the barrier -> VGPR ~75,
// 5 blocks/CU).
__global__ void __launch_bounds__(256, 5) cga_kernel(
    const float* __restrict__ feats,
    const float* __restrict__ Wq, const float* __restrict__ bq,
    const float* __restrict__ Wk, const float* __restrict__ bk,
    const float* __restrict__ Wv, const float* __restrict__ bv,
    const float* __restrict__ Wo, const float* __restrict__ bo,
    const float* __restrict__ corr,
    const float* __restrict__ temp,
    float* __restrict__ out)
{
    __shared__ __align__(16) float feat_s[BB * NPAD];
    __shared__ __align__(16) float k_s[BB * NPAD];
    __shared__ __align__(16) float v_s[BB * NPAD];
    __shared__ __align__(16) float c_s[NPAD];
    __shared__ __align__(16) float bo_s[NPAD];
    __shared__ __align__(16) float wq_s[N * NPAD];
    __shared__ __align__(16) float wk_s[N * NPAD];
    __shared__ __align__(16) float wv_s[N * NPAD];
    __shared__ __align__(16) float out_s[OUT_PER_G];

    const int t  = threadIdx.x;
    const int b0 = blockIdx.x * BB;
    const int bl = t / N;          // local batch 0..12 (t < 247)
    const int i  = t - bl * N;     // query row 0..18
    const bool active = (t < ROWS);

    // ---- phase 1: stage features (coalesced), QKV weights, c, bo ----
    if (active) {
        int gidx = b0 * N + t;
        // tail block: out-of-range batches read as 0 -> finite garbage rows
        // in out_s that the store phase never writes back.
        feat_s[bl * NPAD + i] = (gidx < B_TOTAL * N) ? feats[gidx] : 0.f;
    }
    {
        // cooperative weight staging: 361 floats x3, coalesced global reads
        int idx = t;
        int r = idx / N, c = idx - r * N;
        wq_s[r * NPAD + c] = Wq[idx];
        wk_s[r * NPAD + c] = Wk[idx];
        wv_s[r * NPAD + c] = Wv[idx];
        idx = t + 256;
        if (idx < N * N) {
            r = idx / N; c = idx - r * N;
            wq_s[r * NPAD + c] = Wq[idx];
            wk_s[r * NPAD + c] = Wk[idx];
            wv_s[r * NPAD + c] = Wv[idx];
        }
    }
    if (t < N) {
        float s = 0.f;
#pragma unroll
        for (int r = 0; r < N; ++r) s += corr[r * N + t];
        c_s[t]  = s * (1.0f / N);
        bo_s[t] = bo[t];
    }
    const float invT = 1.0f / temp[0];
    __syncthreads();

    // ---- phase 2: Q/K/V projections (weight rows from LDS, b128 reads) ----
    float q_i = 0.f, k_i = 0.f, v_i = 0.f;
    if (active) {
        float f[NPAD];
        const float4* fp = (const float4*)(&feat_s[bl * NPAD]);
#pragma unroll
        for (int c4 = 0; c4 < 5; ++c4) {
            float4 x = fp[c4];
            f[c4*4+0] = x.x; f[c4*4+1] = x.y; f[c4*4+2] = x.z; f[c4*4+3] = x.w;
        }
        q_i = bq[i]; k_i = bk[i]; v_i = bv[i];
        const float4* wq4 = (const float4*)(&wq_s[i * NPAD]);
        const float4* wk4 = (const float4*)(&wk_s[i * NPAD]);
        const float4* wv4 = (const float4*)(&wv_s[i * NPAD]);
#pragma unroll
        for (int c4 = 0; c4 < 5; ++c4) {
            const int j0 = 4 * c4;
            float4 aq = wq4[c4], ak = wk4[c4], av = wv4[c4];
            q_i = fmaf(f[j0+0], aq.x, q_i);
            k_i = fmaf(f[j0+0], ak.x, k_i);
            v_i = fmaf(f[j0+0], av.x, v_i);
            q_i = fmaf(f[j0+1], aq.y, q_i);
            k_i = fmaf(f[j0+1], ak.y, k_i);
            v_i = fmaf(f[j0+1], av.y, v_i);
            q_i = fmaf(f[j0+2], aq.z, q_i);
            k_i = fmaf(f[j0+2], ak.z, k_i);
            v_i = fmaf(f[j0+2], av.z, v_i);
            if (j0 + 3 < N) {           // compile-time folded: skips j=19 pad
                q_i = fmaf(f[j0+3], aq.w, q_i);
                k_i = fmaf(f[j0+3], ak.w, k_i);
                v_i = fmaf(f[j0+3], av.w, v_i);
            }
        }
        k_s[bl * NPAD + i] = k_i;
        v_s[bl * NPAD + i] = v_i;
    }
    __syncthreads();

    // ---- phase 3: cw, softmax (fused with V), Wo contraction (SGPR rows) ----
    if (active) {
        float K[NPAD], V[NPAD];
        const float4* kp = (const float4*)(&k_s[bl * NPAD]);
        const float4* vp = (const float4*)(&v_s[bl * NPAD]);
#pragma unroll
        for (int c4 = 0; c4 < 5; ++c4) {
            float4 x = kp[c4];
            K[c4*4+0] = x.x; K[c4*4+1] = x.y; K[c4*4+2] = x.z; K[c4*4+3] = x.w;
            float4 y = vp[c4];
            V[c4*4+0] = y.x; V[c4*4+1] = y.y; V[c4*4+2] = y.z; V[c4*4+3] = y.w;
        }
        float cw = 0.f;
#pragma unroll
        for (int j = 0; j < N; ++j) cw = fmaf(c_s[j], K[j], cw);
        const float a = q_i * cw * invT;

        float m = -1e30f;
#pragma unroll
        for (int j = 0; j < N; ++j) m = fmaxf(m, a * K[j]);
        float z = 0.f;
        float p[N];
#pragma unroll
        for (int j = 0; j < N; ++j) {
            float e = __expf(fmaf(a, K[j], -m));
            p[j] = e * V[j];
            z += e;
        }
        const float invZ = 1.0f / z;

        // contraction: Wo row k loaded via scalar pipe (s_load) so the 361
        // fetches never touch VMEM issue slots. The in-asm lgkmcnt(0) plus
        // "=s" outputs carry the dependence (compiler cannot hoist the FMAs).
        const int obase = t * N;
        const int fbase = bl * NPAD;
#pragma unroll
        for (int k = 0; k < N; ++k) {
            sfloat16 w0; sfloat2 w1; float w2;
            asm volatile(
                "s_load_dwordx16 %0, %3, %4\n\t"
                "s_load_dwordx2  %1, %3, %5\n\t"
                "s_load_dword    %2, %3, %6\n\t"
                "s_waitcnt lgkmcnt(0)"
                : "=s"(w0), "=s"(w1), "=s"(w2)
                : "s"(Wo), "i"(k * 76), "i"(k * 76 + 64), "i"(k * 76 + 72));
            float acc = 0.f;
#pragma unroll
            for (int j = 0; j < 16; ++j) acc = fmaf(p[j], w0[j], acc);
            acc = fmaf(p[16], w1[0], acc);
            acc = fmaf(p[17], w1[1], acc);
            acc = fmaf(p[18], w2,    acc);
            out_s[obase + k] = feat_s[fbase + k] + bo_s[k] + acc * invZ;
        }
    }
    __syncthreads();

    // ---- phase 4: flat, fully-coalesced store of 13*361 staged floats ----
    const int outbase = b0 * (N * N);
#pragma unroll
    for (int r = 0; r < (OUT_PER_G + 255) / 256; ++r) {
        int idx = r * 256 + t;
        int go  = outbase + idx;
        if (idx < OUT_PER_G && go < B_TOTAL * N * N)
            out[go] = out_s[idx];
    }
}

extern "C" void kernel_launch(void* const* d_in, const int* in_sizes, int n_in,
                              void* d_out, int out_size, void* d_ws, size_t ws_size,
                              hipStream_t stream) {
    const float* feats = (const float*)d_in[0];
    const float* Wq    = (const float*)d_in[1];
    const float* bq    = (const float*)d_in[2];
    const float* Wk    = (const float*)d_in[3];
    const float* bk    = (const float*)d_in[4];
    const float* Wv    = (const float*)d_in[5];
    const float* bv    = (const float*)d_in[6];
    const float* Wo    = (const float*)d_in[7];
    const float* bo    = (const float*)d_in[8];
    const float* corr  = (const float*)d_in[9];
    const float* temp  = (const float*)d_in[10];
    float* out = (float*)d_out;

    cga_kernel<<<NBLOCKS, 256, 0, stream>>>(feats, Wq, bq, Wk, bk, Wv, bv,
                                            Wo, bo, corr, temp, out);
}

// Round 3
// 247.768 us; speedup vs baseline: 1.0125x; 1.0125x over previous
//
#include <hip/hip_runtime.h>

#define B_TOTAL 131072
#define N 19
#define BB 16                  // batches per block (16*19 = 304 active of 320)
#define ROWS (BB * N)          // 304
#define NT 320                 // 5 waves
#define NPAD 20                // padded row: 80 B, 16B-aligned rows for float4 LDS reads
#define OUT_PER_G (BB * N * N) // 5776 floats staged per block (23104 B, 16B-aligned!)
#define NBLOCKS (B_TOTAL / BB) // 8192, exact -> NO tail block, no store predicates

// One block = 16 batches. One thread = one (batch, query-row i).
//   out[b,i,k] = feat[b,k] + bo[k] + invZ_i * sum_j exp(a_i*K_j - m_i)*V_j*Wo[k,j]
// v3 (resubmit; round-2 run died to a container-acquisition failure, not the
// kernel): (1) Wo via uniform C++ loads -> compiler-pipelined s_load batches
// on the scalar pipe (v2's hand-rolled per-row lgkmcnt(0) serialization cost
// ~5us). (2) BB=16: per-block output span = 23104 B = 0 mod 16, so the store
// phase is pure global_store_dwordx4 (4x fewer store issues) and the exact
// 8192-block grid drops all tail predicates. LDS 31.7KB -> 4 blocks/CU.
__global__ void __launch_bounds__(NT, 5) cga_kernel(
    const float* __restrict__ feats,
    const float* __restrict__ Wq, const float* __restrict__ bq,
    const float* __restrict__ Wk, const float* __restrict__ bk,
    const float* __restrict__ Wv, const float* __restrict__ bv,
    const float* __restrict__ Wo, const float* __restrict__ bo,
    const float* __restrict__ corr,
    const float* __restrict__ temp,
    float* __restrict__ out)
{
    __shared__ __align__(16) float feat_s[BB * NPAD];
    __shared__ __align__(16) float k_s[BB * NPAD];
    __shared__ __align__(16) float v_s[BB * NPAD];
    __shared__ __align__(16) float c_s[NPAD];
    __shared__ __align__(16) float bo_s[NPAD];
    __shared__ __align__(16) float wq_s[N * NPAD];
    __shared__ __align__(16) float wk_s[N * NPAD];
    __shared__ __align__(16) float wv_s[N * NPAD];
    __shared__ __align__(16) float out_s[OUT_PER_G];

    const int t  = threadIdx.x;
    const int b0 = blockIdx.x * BB;
    const int bl = t / N;          // local batch 0..15 (t < 304)
    const int i  = t - bl * N;     // query row 0..18
    const bool active = (t < ROWS);

    // ---- phase 1: stage features (coalesced), QKV weights, c, bo ----
    if (active) {
        feat_s[bl * NPAD + i] = feats[b0 * N + t];   // exact grid: always in range
    }
    {
        // cooperative weight staging: 361 floats x3, coalesced global reads
        int idx = t;                                  // t < 320 < 361: all threads
        int r = idx / N, c = idx - r * N;
        wq_s[r * NPAD + c] = Wq[idx];
        wk_s[r * NPAD + c] = Wk[idx];
        wv_s[r * NPAD + c] = Wv[idx];
        idx = t + NT;
        if (idx < N * N) {                            // 41 threads
            r = idx / N; c = idx - r * N;
            wq_s[r * NPAD + c] = Wq[idx];
            wk_s[r * NPAD + c] = Wk[idx];
            wv_s[r * NPAD + c] = Wv[idx];
        }
    }
    if (t < N) {
        float s = 0.f;
#pragma unroll
        for (int r = 0; r < N; ++r) s += corr[r * N + t];
        c_s[t]  = s * (1.0f / N);
        bo_s[t] = bo[t];
    }
    const float invT = 1.0f / temp[0];
    __syncthreads();

    // ---- phase 2: Q/K/V projections (weight rows from LDS, b128 reads) ----
    float q_i = 0.f, k_i = 0.f, v_i = 0.f;
    if (active) {
        float f[NPAD];
        const float4* fp = (const float4*)(&feat_s[bl * NPAD]);
#pragma unroll
        for (int c4 = 0; c4 < 5; ++c4) {
            float4 x = fp[c4];
            f[c4*4+0] = x.x; f[c4*4+1] = x.y; f[c4*4+2] = x.z; f[c4*4+3] = x.w;
        }
        q_i = bq[i]; k_i = bk[i]; v_i = bv[i];
        const float4* wq4 = (const float4*)(&wq_s[i * NPAD]);
        const float4* wk4 = (const float4*)(&wk_s[i * NPAD]);
        const float4* wv4 = (const float4*)(&wv_s[i * NPAD]);
#pragma unroll
        for (int c4 = 0; c4 < 5; ++c4) {
            const int j0 = 4 * c4;
            float4 aq = wq4[c4], ak = wk4[c4], av = wv4[c4];
            q_i = fmaf(f[j0+0], aq.x, q_i);
            k_i = fmaf(f[j0+0], ak.x, k_i);
            v_i = fmaf(f[j0+0], av.x, v_i);
            q_i = fmaf(f[j0+1], aq.y, q_i);
            k_i = fmaf(f[j0+1], ak.y, k_i);
            v_i = fmaf(f[j0+1], av.y, v_i);
            q_i = fmaf(f[j0+2], aq.z, q_i);
            k_i = fmaf(f[j0+2], ak.z, k_i);
            v_i = fmaf(f[j0+2], av.z, v_i);
            if (j0 + 3 < N) {           // compile-time folded: skips j=19 pad
                q_i = fmaf(f[j0+3], aq.w, q_i);
                k_i = fmaf(f[j0+3], ak.w, k_i);
                v_i = fmaf(f[j0+3], av.w, v_i);
            }
        }
        k_s[bl * NPAD + i] = k_i;
        v_s[bl * NPAD + i] = v_i;
    }
    __syncthreads();

    // ---- phase 3: cw, softmax (fused with V), Wo contraction ----
    if (active) {
        float K[NPAD], V[NPAD];
        const float4* kp = (const float4*)(&k_s[bl * NPAD]);
        const float4* vp = (const float4*)(&v_s[bl * NPAD]);
#pragma unroll
        for (int c4 = 0; c4 < 5; ++c4) {
            float4 x = kp[c4];
            K[c4*4+0] = x.x; K[c4*4+1] = x.y; K[c4*4+2] = x.z; K[c4*4+3] = x.w;
            float4 y = vp[c4];
            V[c4*4+0] = y.x; V[c4*4+1] = y.y; V[c4*4+2] = y.z; V[c4*4+3] = y.w;
        }
        float cw = 0.f;
#pragma unroll
        for (int j = 0; j < N; ++j) cw = fmaf(c_s[j], K[j], cw);
        const float a = q_i * cw * invT;

        float m = -1e30f;
#pragma unroll
        for (int j = 0; j < N; ++j) m = fmaxf(m, a * K[j]);
        float z = 0.f;
        float p[N];
#pragma unroll
        for (int j = 0; j < N; ++j) {
            float e = __expf(fmaf(a, K[j], -m));
            p[j] = e * V[j];
            z += e;
        }
        const float invZ = 1.0f / z;

        // contraction: Wo[k*N+j] is wave-uniform -> compiler emits pipelined
        // s_load batches on the scalar pipe (v1 behavior; do NOT hand-roll).
        const int obase = t * N;
        const int fbase = bl * NPAD;
#pragma unroll
        for (int k = 0; k < N; ++k) {
            float acc = 0.f;
#pragma unroll
            for (int j = 0; j < N; ++j) acc = fmaf(p[j], Wo[k * N + j], acc);
            out_s[obase + k] = feat_s[fbase + k] + bo_s[k] + acc * invZ;
        }
    }
    __syncthreads();

    // ---- phase 4: flat, fully-coalesced dwordx4 store (16B-aligned span) ----
    {
        const float4* src = (const float4*)out_s;
        float4* dst = (float4*)(out + (size_t)blockIdx.x * OUT_PER_G);
#pragma unroll
        for (int r = 0; r < (OUT_PER_G / 4 + NT - 1) / NT; ++r) {
            int idx = r * NT + t;
            if (idx < OUT_PER_G / 4) dst[idx] = src[idx];
        }
    }
}

extern "C" void kernel_launch(void* const* d_in, const int* in_sizes, int n_in,
                              void* d_out, int out_size, void* d_ws, size_t ws_size,
                              hipStream_t stream) {
    const float* feats = (const float*)d_in[0];
    const float* Wq    = (const float*)d_in[1];
    const float* bq    = (const float*)d_in[2];
    const float* Wk    = (const float*)d_in[3];
    const float* bk    = (const float*)d_in[4];
    const float* Wv    = (const float*)d_in[5];
    const float* bv    = (const float*)d_in[6];
    const float* Wo    = (const float*)d_in[7];
    const float* bo    = (const float*)d_in[8];
    const float* corr  = (const float*)d_in[9];
    const float* temp  = (const float*)d_in[10];
    float* out = (float*)d_out;

    cga_kernel<<<NBLOCKS, NT, 0, stream>>>(feats, Wq, bq, Wk, bk, Wv, bv,
                                           Wo, bo, corr, temp, out);
}